// Round 11
// baseline (589.460 us; speedup 1.0000x reference)
//
#include <hip/hip_runtime.h>
#include <math.h>

// HungarianLoss: B=4096 independent 32x32 degenerate-JV problems + matched loss.
// One wave per batch; lane <-> column (duplicated into lanes 32..63).
//
// Reference semantics (its _lsa_square never writes back minv/way):
//   for row i: j0=0; used={}; p[0]=i
//     loop: used+={j0}; i0=p[j0]
//           j1 = argmin_{free j}(cost[i0-1][j] - u[i0] - v[j]); delta = that min
//           u[p[used]] += delta; v[used] -= delta
//           j0=j1; if p[j0]==0 break
//     p[j0] = i   // only terminal column assigned
//
// r10 lesson (VGPR_Count=28): a switch-over-array select gets canonicalized by
// LLVM back into a dynamic index -> cc[] lands in SCRATCH (~200cy/step, slower
// than the LDS read it replaced). This round selects via a fully-unrolled
// v_cndmask binary tree (constant indices only, 5 uniform condition bits) --
// no dynamically-indexable storage exists, so cc[] must stay in VGPRs.
// All FP ops remain bitwise-identical to the r6 kernel (passed absmax 0.0).

constexpr int BB = 4096;
constexpr int NN = 32;
constexpr int TT = 8;
constexpr float ALPHA_F = 1.0f;
constexpr float BETA_F  = 0.5f;
constexpr float EPS_F   = 1e-8f;

template <int CTRL, int ROW_MASK>
__device__ __forceinline__ float dpp_min(float x) {
    int t = __builtin_amdgcn_update_dpp(__float_as_int(x), __float_as_int(x),
                                        CTRL, ROW_MASK, 0xf, false);
    return fminf(x, __int_as_float(t));
}

// Min over each 32-lane half (halves hold identical data); broadcast via SGPR.
__device__ __forceinline__ float wave32_min_bcast(float x) {
    x = dpp_min<0xB1,  0xf>(x); // quad_perm [1,0,3,2]  (xor 1)
    x = dpp_min<0x4E,  0xf>(x); // quad_perm [2,3,0,1]  (xor 2)
    x = dpp_min<0x124, 0xf>(x); // row_ror:4
    x = dpp_min<0x128, 0xf>(x); // row_ror:8   -> per-16-row min
    x = dpp_min<0x142, 0xa>(x); // row_bcast15 -> rows 1,3 have 32-min
    return __int_as_float(__builtin_amdgcn_readlane(__float_as_int(x), 31));
}

__device__ __forceinline__ float readlane_f(float x, int lane) {
    return __int_as_float(__builtin_amdgcn_readlane(__float_as_int(x), lane));
}

// Uniform-index select from 32 register-resident floats via a cndmask tree.
// Every array index is a compile-time constant; the wave-uniform runtime index
// only appears as 5 boolean conditions -> 31 v_cndmask, zero memory traffic.
__device__ __forceinline__ float sel32_tree(const float (&cc)[NN], int r) {
    const bool b4 = (r & 16) != 0, b3 = (r & 8) != 0, b2 = (r & 4) != 0;
    const bool b1 = (r & 2)  != 0, b0 = (r & 1) != 0;
    float t[16];
#pragma unroll
    for (int k = 0; k < 16; ++k) t[k] = b4 ? cc[k + 16] : cc[k];
    float s[8];
#pragma unroll
    for (int k = 0; k < 8; ++k)  s[k] = b3 ? t[k + 8]  : t[k];
    float q[4];
#pragma unroll
    for (int k = 0; k < 4; ++k)  q[k] = b2 ? s[k + 4]  : s[k];
    const float d0 = b1 ? q[2] : q[0];
    const float d1 = b1 ? q[3] : q[1];
    return b0 ? d1 : d0;
}

__global__ __launch_bounds__(256) void hungarian_lsa_kernel(
    const float* __restrict__ pred_j,
    const float* __restrict__ logits,
    const float* __restrict__ target_j,
    const int*   __restrict__ target_types,
    double* __restrict__ partials)
{
    __shared__ float lgpS[4][NN * TT];   // log(softmax+eps), 1 KB/wave
    __shared__ float lgtS[4][NN * TT];   // raw logits for epilogue gather

    const int wave = threadIdx.x >> 6;
    const int lane = threadIdx.x & 63;
    const int col  = lane & 31;
    const int b    = blockIdx.x * 4 + wave;

    float* lgp = lgpS[wave];
    float* lgt = lgtS[wave];

    // ---- per-lane row data (lane r <-> row r) ----
    const float pj = pred_j  [b * NN + col];
    const float tj = target_j[b * NN + col];
    const int   tt = target_types[b * NN + col];

    float x[TT];
    const float* lrow = logits + ((size_t)b * NN + col) * TT;
#pragma unroll
    for (int t = 0; t < TT; ++t) x[t] = lrow[t];

    float m = x[0]; int am = 0;
#pragma unroll
    for (int t = 1; t < TT; ++t) { if (x[t] > m) { m = x[t]; am = t; } }
    float s = 0.f;
#pragma unroll
    for (int t = 0; t < TT; ++t) s += expf(x[t] - m);
    const float lse = m + logf(s);

    if (lane < 32) {
#pragma unroll
        for (int t = 0; t < TT; ++t) {
            float p = expf(x[t] - m) / s;
            lgp[col * TT + t] = logf(p + EPS_F);
            lgt[col * TT + t] = x[t];
        }
    }
    __syncthreads();

    // ---- cost column in registers: cc[r] = cost[r][col] (constant indices) ----
    float cc[NN];
#pragma unroll
    for (int r = 0; r < NN; ++r) {
        const float pjr = readlane_f(pj, r);           // row r's pred_j (uniform)
        const float lp  = lgp[r * TT + tt];            // LDS gather, pipelined
        cc[r] = ALPHA_F * fabsf(pjr - tj) + BETA_F * (-lp);
    }

    // ---- degenerate shortest-path walks ----
    const float INFF = __builtin_inff();
    float v_f  = 0.0f;    // v[col+1]
    float uc_f = 0.0f;    // u[p[col+1]] (valid once col assigned)
    int   p_i  = 0;       // row assigned to col+1 (1-based)
    unsigned amask = 0;   // bit j-1 set <=> col j assigned (wave-uniform)

    for (int i = 1; i <= NN; ++i) {
        bool used_b = false;

        // step 0: i0 = i (new row), no cols used yet, u[i]=0
        float cur = sel32_tree(cc, i - 1) - v_f;
        float mv  = wave32_min_bcast(cur);
        unsigned long long bm = __ballot(cur == mv);
        int   j1      = __ffsll(bm);       // 1-based col (lowest lane = lowest col)
        float rowSum  = mv;                // u[i] accumulates every delta this walk

        while ((amask >> (j1 - 1)) & 1u) { // chosen col occupied -> continue walk
            const int j0 = j1;
            used_b |= (col == j0 - 1);
            const int   r0    = __builtin_amdgcn_readlane(p_i, j0 - 1) - 1; // row of j0
            const float uc_j0 = readlane_f(uc_f, j0 - 1);                   // u[p[j0]]
            const float cur2  = sel32_tree(cc, r0) - v_f;
            const float curm  = used_b ? INFF : cur2;
            mv = wave32_min_bcast(curm);
            bm = __ballot((!used_b) && (cur2 == mv));
            j1 = __ffsll(bm);
            const float delta = mv - uc_j0;
            rowSum += delta;
            if (used_b) { v_f -= delta; uc_f += delta; }
        }

        // terminal column j1: assign row i
        if (col == j1 - 1) { p_i = i; uc_f = rowSum; }
        amask |= 1u << (j1 - 1);
    }

    // ---- matched loss contributions (column-centric; bijection == row sum) ----
    const int   row      = p_i - 1;
    const float pj_row   = __shfl(pj,  row);
    const float lse_row  = __shfl(lse, row);
    const int   am_row   = __shfl(am,  row);
    const float logit_tt = lgt[row * TT + tt];

    double sj = (lane < 32) ? (double)fabsf(pj_row - tj)   : 0.0;
    double st = (lane < 32) ? (double)(lse_row - logit_tt) : 0.0;
    double sa = (lane < 32) ? ((am_row == tt) ? 1.0 : 0.0) : 0.0;
#pragma unroll
    for (int off = 32; off >= 1; off >>= 1) {
        sj += __shfl_xor(sj, off);
        st += __shfl_xor(st, off);
        sa += __shfl_xor(sa, off);
    }
    if (lane == 0) {
        partials[b * 3 + 0] = sj;
        partials[b * 3 + 1] = st;
        partials[b * 3 + 2] = sa;
    }
}

__global__ __launch_bounds__(256) void hungarian_finalize_kernel(
    const double* __restrict__ partials, float* __restrict__ out)
{
    __shared__ double sm0[256], sm1[256], sm2[256];
    const int tid = threadIdx.x;
    double a = 0.0, c = 0.0, e = 0.0;
    for (int i = tid; i < BB; i += 256) {
        a += partials[i * 3 + 0];
        c += partials[i * 3 + 1];
        e += partials[i * 3 + 2];
    }
    sm0[tid] = a; sm1[tid] = c; sm2[tid] = e;
    __syncthreads();
    for (int s = 128; s > 0; s >>= 1) {
        if (tid < s) {
            sm0[tid] += sm0[tid + s];
            sm1[tid] += sm1[tid + s];
            sm2[tid] += sm2[tid + s];
        }
        __syncthreads();
    }
    if (tid == 0) {
        const double jl = sm0[0], tl = sm1[0], ac = sm2[0];
        const double total = (double)BB * (double)NN;
        out[0] = (float)((jl + 0.5 * tl) / total);  // loss
        out[1] = (float)(jl / total);               // j_mae
        out[2] = (float)(ac / total);               // type_acc
    }
}

extern "C" void kernel_launch(void* const* d_in, const int* in_sizes, int n_in,
                              void* d_out, int out_size, void* d_ws, size_t ws_size,
                              hipStream_t stream) {
    const float* pred_j       = (const float*)d_in[0];
    const float* logits       = (const float*)d_in[1];
    const float* target_j     = (const float*)d_in[2];
    const int*   target_types = (const int*)  d_in[3];

    double* partials = (double*)d_ws;   // 4096*3 doubles = 96 KB
    float*  out      = (float*)d_out;

    hungarian_lsa_kernel<<<BB / 4, 256, 0, stream>>>(
        pred_j, logits, target_j, target_types, partials);
    hungarian_finalize_kernel<<<1, 256, 0, stream>>>(partials, out);
}

// Round 12
// 49.872 us; speedup vs baseline: 11.8195x; 11.8195x over previous
//
#include <hip/hip_runtime.h>
#include <math.h>

// HungarianLoss: B=4096 independent 32x32 degenerate-JV problems + matched loss.
// One wave per batch; lane <-> column (duplicated into lanes 32..63).
//
// Reference semantics (its _lsa_square never writes back minv/way):
//   for row i: j0=0; used={}; p[0]=i
//     loop: used+={j0}; i0=p[j0]
//           j1 = argmin_{free j}(cost[i0-1][j] - u[i0] - v[j]); delta = that min
//           u[p[used]] += delta; v[used] -= delta
//           j0=j1; if p[j0]==0 break
//     p[j0] = i   // only terminal column assigned
//
// r10/r11 lessons: switch-select AND cndmask-tree both get canonicalized by
// LLVM into dynamic indexing -> alloca -> SCRATCH (r11: VGPR=20, 1.3GB spill
// traffic/dispatch, 590us). This round uses the HW primitive for the job:
// ext_vector_type(32) float + wave-uniform extract index -> extractelement
// with SGPR index -> s_mov m0; v_movrels_b32 (register-indexed VGPR read,
// ~8cy, no memory). All FP ops bitwise-identical to r6 (passed absmax 0.0).

constexpr int BB = 4096;
constexpr int NN = 32;
constexpr int TT = 8;
constexpr float ALPHA_F = 1.0f;
constexpr float BETA_F  = 0.5f;
constexpr float EPS_F   = 1e-8f;

typedef float f32x32 __attribute__((ext_vector_type(32)));

template <int CTRL, int ROW_MASK>
__device__ __forceinline__ float dpp_min(float x) {
    int t = __builtin_amdgcn_update_dpp(__float_as_int(x), __float_as_int(x),
                                        CTRL, ROW_MASK, 0xf, false);
    return fminf(x, __int_as_float(t));
}

// Min over each 32-lane half (halves hold identical data); broadcast via SGPR.
// Verified bit-exact on HW in r6/r10 (absmax 0.0).
__device__ __forceinline__ float wave32_min_bcast(float x) {
    x = dpp_min<0xB1,  0xf>(x); // quad_perm [1,0,3,2]  (xor 1)
    x = dpp_min<0x4E,  0xf>(x); // quad_perm [2,3,0,1]  (xor 2)
    x = dpp_min<0x124, 0xf>(x); // row_ror:4
    x = dpp_min<0x128, 0xf>(x); // row_ror:8   -> per-16-row min
    x = dpp_min<0x142, 0xa>(x); // row_bcast15 -> rows 1,3 have 32-min
    return __int_as_float(__builtin_amdgcn_readlane(__float_as_int(x), 31));
}

__device__ __forceinline__ float readlane_f(float x, int lane) {
    return __int_as_float(__builtin_amdgcn_readlane(__float_as_int(x), lane));
}

__global__ __launch_bounds__(256) void hungarian_lsa_kernel(
    const float* __restrict__ pred_j,
    const float* __restrict__ logits,
    const float* __restrict__ target_j,
    const int*   __restrict__ target_types,
    double* __restrict__ partials)
{
    __shared__ float lgpS[4][NN * TT];   // log(softmax+eps), 1 KB/wave
    __shared__ float lgtS[4][NN * TT];   // raw logits for epilogue gather

    const int wave = threadIdx.x >> 6;
    const int lane = threadIdx.x & 63;
    const int col  = lane & 31;
    const int b    = blockIdx.x * 4 + wave;

    float* lgp = lgpS[wave];
    float* lgt = lgtS[wave];

    // ---- per-lane row data (lane r <-> row r) ----
    const float pj = pred_j  [b * NN + col];
    const float tj = target_j[b * NN + col];
    const int   tt = target_types[b * NN + col];

    float x[TT];
    const float* lrow = logits + ((size_t)b * NN + col) * TT;
#pragma unroll
    for (int t = 0; t < TT; ++t) x[t] = lrow[t];

    float m = x[0]; int am = 0;
#pragma unroll
    for (int t = 1; t < TT; ++t) { if (x[t] > m) { m = x[t]; am = t; } }
    float s = 0.f;
#pragma unroll
    for (int t = 0; t < TT; ++t) s += expf(x[t] - m);
    const float lse = m + logf(s);

    if (lane < 32) {
#pragma unroll
        for (int t = 0; t < TT; ++t) {
            float p = expf(x[t] - m) / s;
            lgp[col * TT + t] = logf(p + EPS_F);
            lgt[col * TT + t] = x[t];
        }
    }
    __syncthreads();

    // ---- cost column as a 32-wide register vector: cc[r] = cost[r][col] ----
    // Built with constant-index inserts; consumed with wave-uniform extracts
    // (-> v_movrels_b32, stays in 32 contiguous VGPRs, never memory).
    f32x32 cc;
#pragma unroll
    for (int r = 0; r < NN; ++r) {
        const float pjr = readlane_f(pj, r);           // row r's pred_j (uniform)
        const float lp  = lgp[r * TT + tt];            // LDS gather, pipelined
        cc[r] = ALPHA_F * fabsf(pjr - tj) + BETA_F * (-lp);
    }

    // ---- degenerate shortest-path walks ----
    const float INFF = __builtin_inff();
    float v_f  = 0.0f;    // v[col+1]
    float uc_f = 0.0f;    // u[p[col+1]] (valid once col assigned)
    int   p_i  = 0;       // row assigned to col+1 (1-based)
    unsigned amask = 0;   // bit j-1 set <=> col j assigned (wave-uniform)

    for (int i = 1; i <= NN; ++i) {
        bool used_b = false;

        // step 0: i0 = i (new row), no cols used yet, u[i]=0
        float cur = cc[i - 1] - v_f;                  // uniform idx -> movrels
        float mv  = wave32_min_bcast(cur);
        unsigned long long bm = __ballot(cur == mv);
        int   j1      = __ffsll(bm);       // 1-based col (lowest lane = lowest col)
        float rowSum  = mv;                // u[i] accumulates every delta this walk

        while ((amask >> (j1 - 1)) & 1u) { // chosen col occupied -> continue walk
            const int j0 = j1;
            used_b |= (col == j0 - 1);
            const int   r0    = __builtin_amdgcn_readlane(p_i, j0 - 1) - 1; // row of j0 (uniform)
            const float uc_j0 = readlane_f(uc_f, j0 - 1);                   // u[p[j0]]
            const float cur2  = cc[r0] - v_f;          // uniform idx -> movrels
            const float curm  = used_b ? INFF : cur2;
            mv = wave32_min_bcast(curm);
            bm = __ballot((!used_b) && (cur2 == mv));
            j1 = __ffsll(bm);
            const float delta = mv - uc_j0;
            rowSum += delta;
            if (used_b) { v_f -= delta; uc_f += delta; }
        }

        // terminal column j1: assign row i
        if (col == j1 - 1) { p_i = i; uc_f = rowSum; }
        amask |= 1u << (j1 - 1);
    }

    // ---- matched loss contributions (column-centric; bijection == row sum) ----
    const int   row      = p_i - 1;
    const float pj_row   = __shfl(pj,  row);
    const float lse_row  = __shfl(lse, row);
    const int   am_row   = __shfl(am,  row);
    const float logit_tt = lgt[row * TT + tt];

    double sj = (lane < 32) ? (double)fabsf(pj_row - tj)   : 0.0;
    double st = (lane < 32) ? (double)(lse_row - logit_tt) : 0.0;
    double sa = (lane < 32) ? ((am_row == tt) ? 1.0 : 0.0) : 0.0;
#pragma unroll
    for (int off = 32; off >= 1; off >>= 1) {
        sj += __shfl_xor(sj, off);
        st += __shfl_xor(st, off);
        sa += __shfl_xor(sa, off);
    }
    if (lane == 0) {
        partials[b * 3 + 0] = sj;
        partials[b * 3 + 1] = st;
        partials[b * 3 + 2] = sa;
    }
}

__global__ __launch_bounds__(256) void hungarian_finalize_kernel(
    const double* __restrict__ partials, float* __restrict__ out)
{
    __shared__ double sm0[256], sm1[256], sm2[256];
    const int tid = threadIdx.x;
    double a = 0.0, c = 0.0, e = 0.0;
    for (int i = tid; i < BB; i += 256) {
        a += partials[i * 3 + 0];
        c += partials[i * 3 + 1];
        e += partials[i * 3 + 2];
    }
    sm0[tid] = a; sm1[tid] = c; sm2[tid] = e;
    __syncthreads();
    for (int s = 128; s > 0; s >>= 1) {
        if (tid < s) {
            sm0[tid] += sm0[tid + s];
            sm1[tid] += sm1[tid + s];
            sm2[tid] += sm2[tid + s];
        }
        __syncthreads();
    }
    if (tid == 0) {
        const double jl = sm0[0], tl = sm1[0], ac = sm2[0];
        const double total = (double)BB * (double)NN;
        out[0] = (float)((jl + 0.5 * tl) / total);  // loss
        out[1] = (float)(jl / total);               // j_mae
        out[2] = (float)(ac / total);               // type_acc
    }
}

extern "C" void kernel_launch(void* const* d_in, const int* in_sizes, int n_in,
                              void* d_out, int out_size, void* d_ws, size_t ws_size,
                              hipStream_t stream) {
    const float* pred_j       = (const float*)d_in[0];
    const float* logits       = (const float*)d_in[1];
    const float* target_j     = (const float*)d_in[2];
    const int*   target_types = (const int*)  d_in[3];

    double* partials = (double*)d_ws;   // 4096*3 doubles = 96 KB
    float*  out      = (float*)d_out;

    hungarian_lsa_kernel<<<BB / 4, 256, 0, stream>>>(
        pred_j, logits, target_j, target_types, partials);
    hungarian_finalize_kernel<<<1, 256, 0, stream>>>(partials, out);
}